// Round 6
// baseline (1010.119 us; speedup 1.0000x reference)
//
#include <hip/hip_runtime.h>

#define DD 64
#define HH 256
#define WW 256
#define HW (HH * WW)      // 65536
#define NVOX (DD * HW)    // 4194304

#define TS 32             // output tile (H and W)
#define DR 36             // deriv region = TS+4 (row stride 36, even)
#define HPH 40            // hbuf row stride in HALFS (bank-spread: 2-way free)
#define CHB2 32           // planes per chunk: 2 chunks -> grid z=8 -> 512 blocks = 2/CU
#define NPF 6             // prefetch slots = ceil(DR*DR/256)

typedef __fp16 half2v __attribute__((ext_vector_type(2)));

#if __has_builtin(__builtin_amdgcn_fdot2)
#define FDOT2(a, b, c) __builtin_amdgcn_fdot2((a), (b), (c), false)
#else
#define FDOT2(a, b, c) \
  fmaf((float)(a).x, (float)(b).x, fmaf((float)(a).y, (float)(b).y, (c)))
#endif

// ---------------------------------------------------------------------------
// Kernel A: corr[h,w] = (sino[h,w] - sum_d t[d,h,w]) / DD
// ---------------------------------------------------------------------------
__global__ __launch_bounds__(256) void k_corr(const float* __restrict__ t,
                                              const float* __restrict__ sino,
                                              float* __restrict__ corr) {
  int idx = blockIdx.x * 256 + threadIdx.x;  // 0..HW-1
  float s = 0.f;
#pragma unroll 8
  for (int d = 0; d < DD; ++d) s += t[d * HW + idx];
  corr[idx] = (sino[idx] - s) * (1.0f / DD);
}

// ---------------------------------------------------------------------------
// Kernel B (R9): TWO hidden planes per barrier phase.
// R6/R7/R8 post-mortem: duration pinned at ~305us while VALUBusy swung 61->84
// and LDS traffic varied 40% => neither pipe is the limit; the 2-barrier x 18
// iteration phase skeleton is. R9 halves the phase count (17 phases/block),
// computing hidden planes (e,e+1) from a 4-deep dbuf ring:
//  - conv1 window regs (4 planes x 4 rows) serve BOTH hidden planes
//    (32 b64 reads / 2 planes, was 48; each weight s_load feeds 8 FMAs)
//  - conv2 weight LDS reads amortized 2x (once per ch per phase)
//  - accumulator ring depth 4 (A0..A3), 2 output planes stored per phase
//  - LDS 64.5KB -> 2 blocks/CU (R7 proved occupancy above this is worthless)
// ---------------------------------------------------------------------------
__global__ __launch_bounds__(256, 2) void k_blocks(
    const float* __restrict__ t, const float* __restrict__ corr,
    float* __restrict__ p, float* __restrict__ q, float* __restrict__ s_,
    float* __restrict__ zb,
    const float* __restrict__ W1g, const float* __restrict__ B1g,
    const float* __restrict__ W2g, const float* __restrict__ B2g,
    const float* __restrict__ ntx, const float* __restrict__ nty,
    const float* __restrict__ ntz, const float* __restrict__ nt, int c) {
  __shared__ __align__(16) float dbuf[4][DR][DR];        // 20736 B
  __shared__ __align__(16) __fp16 hbuf[2][8][34][HPH];   // 43520 B
  __shared__ __align__(8) half2v wpkl[72];               // 288 B (64544 total)

  const int b = blockIdx.z & 3;
  const int D0 = (blockIdx.z >> 2) * CHB2;          // 0, 32
  const int ty0 = blockIdx.y * TS;
  const int tx0 = blockIdx.x * TS;
  const int tid = threadIdx.x;
  const bool edgeT = (ty0 == 0) || (ty0 == HH - TS) || (tx0 == 0) || (tx0 == WW - TS);

  const float* w1 = W1g + b * 216;  // [8][3][3][3]
  const float* w2 = W2g + b * 216;  // [8][3][3][3] (W2 shape (4,1,8,3,3,3))
  float b1[8];
#pragma unroll
  for (int ch = 0; ch < 8; ++ch) b1[ch] = B1g[b * 8 + ch];
  const float b2 = B2g[b];
  const float coef = (b == 0) ? ntx[c] : (b == 1) ? nty[c] : (b == 2) ? ntz[c] : nt[c];
  const float* prevBuf = (b == 0) ? p : (b == 1) ? q : (b == 2) ? s_ : t;
  float* outBuf = (b == 0) ? p : (b == 1) ? q : (b == 2) ? s_ : zb;
  const bool zeroPrev = (c == 0) && (b < 3);
  const int strideA = (b == 0) ? 1 : (b == 1) ? WW : HW;

  auto dsl = [](int f) { return (f + 8) & 3; };     // 4-deep ring slot

  // ---- pack conv2 weights (kx0,kx1) as half2 into LDS (once per block)
  if (tid < 72) {
    int ch = tid / 9, pr = tid - ch * 9;     // pr = kz*3+ky
    const float* w = w2 + ch * 27 + pr * 3;
    half2v hv;
    hv.x = (__fp16)w[0];
    hv.y = (__fp16)w[1];
    wpkl[tid] = hv;
  }

  // ---- hoisted per-slot geometry (f-invariant): cbt, load-mask bit, corr diff
  int cbt[NPF];
  float dC[NPF];
  unsigned mbits = 0;
#pragma unroll
  for (int k = 0; k < NPF; ++k) {
    int i = tid + k * 256;
    int iy = i / DR, ix = i - iy * DR;
    int gy = ty0 - 2 + iy, gx = tx0 - 2 + ix;
    bool inb = (i < DR * DR) && ((unsigned)gy < HH) && ((unsigned)gx < WW);
    int cb = gy * WW + gx;
    cbt[k] = cb;
    bool m;
    float d = 0.f;
    if (b == 0) {
      m = inb && (gx + 1 < WW);
      if (m) d = corr[cb + 1] - corr[cb];
    } else if (b == 1) {
      m = inb && (gy + 1 < HH);
      if (m) d = corr[cb + WW] - corr[cb];
    } else if (b == 2) {
      m = inb;
    } else {
      m = inb;
      if (m) d = corr[cb];
    }
    dC[k] = d;
    if (m) mbits |= (1u << k);
  }

  // ---- prefetch regs: two planes in flight (a = even slot, b = odd slot)
  float pA0a[NPF], pA1a[NPF], pA0b[NPF], pA1b[NPF];

  auto issue_one = [&](int f, float (&A0)[NPF], float (&A1)[NPF]) {
    const bool fok = (f >= 0) && (f < DD) && (b != 2 || (f + 1 < DD));
    const int fb = f * HW;
#pragma unroll
    for (int k = 0; k < NPF; ++k) {
      A0[k] = 0.f; A1[k] = 0.f;
      if (fok && ((mbits >> k) & 1u)) {
        const float* base = t + fb + cbt[k];
        A0[k] = base[0];
        if (b != 3) A1[k] = base[strideA];
      }
    }
  };
  auto write_one = [&](int f, float (&A0)[NPF], float (&A1)[NPF]) {
    float* dst = &dbuf[dsl(f)][0][0];
#pragma unroll
    for (int k = 0; k < NPF; ++k) {
      if (k < 5 || tid < (DR * DR - 5 * 256)) {  // i < 1296
        float v = (b == 3) ? (A0[k] + dC[k]) : ((A1[k] - A0[k]) + dC[k]);
        dst[tid + k * 256] = v;
      }
    }
  };

  // ---- conv1 for one 2x2 patch, BOTH hidden planes, channels [ch0,ch1)
  // d0..d3 = dbuf planes e-1,e,e+1,e+2. Plane A (e) uses win[0..2],
  // plane B (e+1) uses win[1..3]; one weight s_load feeds 8 FMAs.
  auto conv1_pair = [&](const float* d0, const float* d1, const float* d2,
                        const float* d3, int jy, int jx, int ch0, int ch1) {
    float win[4][4][4];
#pragma unroll
    for (int r = 0; r < 4; ++r) {
      int off = (jy + r) * DR + jx;
      const float2* q0 = (const float2*)(d0 + off);
      const float2* q1 = (const float2*)(d1 + off);
      const float2* q2 = (const float2*)(d2 + off);
      const float2* q3 = (const float2*)(d3 + off);
      float2 a, bb;
      a = q0[0]; bb = q0[1];
      win[0][r][0] = a.x; win[0][r][1] = a.y; win[0][r][2] = bb.x; win[0][r][3] = bb.y;
      a = q1[0]; bb = q1[1];
      win[1][r][0] = a.x; win[1][r][1] = a.y; win[1][r][2] = bb.x; win[1][r][3] = bb.y;
      a = q2[0]; bb = q2[1];
      win[2][r][0] = a.x; win[2][r][1] = a.y; win[2][r][2] = bb.x; win[2][r][3] = bb.y;
      a = q3[0]; bb = q3[1];
      win[3][r][0] = a.x; win[3][r][1] = a.y; win[3][r][2] = bb.x; win[3][r][3] = bb.y;
    }
    bool in00 = true, in01 = true, in10 = true, in11 = true;
    if (edgeT) {
      int gy0 = ty0 - 1 + jy, gx0 = tx0 - 1 + jx;
      in00 = ((unsigned)gy0 < HH) && ((unsigned)gx0 < WW);
      in01 = ((unsigned)gy0 < HH) && ((unsigned)(gx0 + 1) < WW);
      in10 = ((unsigned)(gy0 + 1) < HH) && ((unsigned)gx0 < WW);
      in11 = ((unsigned)(gy0 + 1) < HH) && ((unsigned)(gx0 + 1) < WW);
    }
#pragma unroll 2
    for (int ch = ch0; ch < ch1; ++ch) {
      float bia = b1[ch];
      float aA00 = bia, aA01 = bia, aA10 = bia, aA11 = bia;
      float aB00 = bia, aB01 = bia, aB10 = bia, aB11 = bia;
      const float* wch = w1 + ch * 27;
#pragma unroll
      for (int kz = 0; kz < 3; ++kz)
#pragma unroll
        for (int ky = 0; ky < 3; ++ky)
#pragma unroll
          for (int kx = 0; kx < 3; ++kx) {
            float wv = wch[kz * 9 + ky * 3 + kx];
            aA00 = fmaf(wv, win[kz][ky][kx], aA00);
            aA01 = fmaf(wv, win[kz][ky][kx + 1], aA01);
            aA10 = fmaf(wv, win[kz][ky + 1][kx], aA10);
            aA11 = fmaf(wv, win[kz][ky + 1][kx + 1], aA11);
            aB00 = fmaf(wv, win[kz + 1][ky][kx], aB00);
            aB01 = fmaf(wv, win[kz + 1][ky][kx + 1], aB01);
            aB10 = fmaf(wv, win[kz + 1][ky + 1][kx], aB10);
            aB11 = fmaf(wv, win[kz + 1][ky + 1][kx + 1], aB11);
          }
      float rA00 = fmaxf(aA00, 0.f), rA01 = fmaxf(aA01, 0.f);
      float rA10 = fmaxf(aA10, 0.f), rA11 = fmaxf(aA11, 0.f);
      float rB00 = fmaxf(aB00, 0.f), rB01 = fmaxf(aB01, 0.f);
      float rB10 = fmaxf(aB10, 0.f), rB11 = fmaxf(aB11, 0.f);
      if (edgeT) {  // block-uniform branch
        rA00 = in00 ? rA00 : 0.f; rA01 = in01 ? rA01 : 0.f;
        rA10 = in10 ? rA10 : 0.f; rA11 = in11 ? rA11 : 0.f;
        rB00 = in00 ? rB00 : 0.f; rB01 = in01 ? rB01 : 0.f;
        rB10 = in10 ? rB10 : 0.f; rB11 = in11 ? rB11 : 0.f;
      }
      *(half2v*)&hbuf[0][ch][jy][jx]     = __builtin_amdgcn_cvt_pkrtz(rA00, rA01);
      *(half2v*)&hbuf[0][ch][jy + 1][jx] = __builtin_amdgcn_cvt_pkrtz(rA10, rA11);
      *(half2v*)&hbuf[1][ch][jy][jx]     = __builtin_amdgcn_cvt_pkrtz(rB00, rB01);
      *(half2v*)&hbuf[1][ch][jy + 1][jx] = __builtin_amdgcn_cvt_pkrtz(rB10, rB11);
    }
  };

  auto comp_hidden_pair = [&](int e) {
    const float* d0 = &dbuf[dsl(e - 1)][0][0];
    const float* d1 = &dbuf[dsl(e)][0][0];
    const float* d2 = &dbuf[dsl(e + 1)][0][0];
    const float* d3 = &dbuf[dsl(e + 2)][0][0];
    {
      int prr = tid / 17, pcc = tid - prr * 17;     // patches 0..255
      conv1_pair(d0, d1, d2, d3, prr * 2, pcc * 2, 0, 8);
    }
    if (tid < 132) {                                 // patches 256..288
      int m = tid >> 2, chp = (tid & 3) << 1;
      int pi = 256 + m;
      int prr = pi / 17, pcc = pi - prr * 17;
      conv1_pair(d0, d1, d2, d3, prr * 2, pcc * 2, chp, chp + 2);
    }
  };

  const int txi = tid & 15, tyi = tid >> 4;
  const int px0 = txi * 2, py0 = tyi * 2;

  // accumulator ring: A0=out(e-1), A1=out(e), A2=out(e+1), A3=out(e+2)
  float A0_[2][2], A1_[2][2], A2_[2][2], A3_[2][2];
#pragma unroll
  for (int i = 0; i < 2; ++i)
#pragma unroll
    for (int j = 0; j < 2; ++j) {
      A0_[i][j] = b2; A1_[i][j] = b2; A2_[i][j] = b2; A3_[i][j] = b2;
    }

  // prologue: dbuf planes D0-2..D0+1 (out-of-range -> zeros)
  issue_one(D0 - 2, pA0a, pA1a); issue_one(D0 - 1, pA0b, pA1b);
  write_one(D0 - 2, pA0a, pA1a); write_one(D0 - 1, pA0b, pA1b);
  issue_one(D0,     pA0a, pA1a); issue_one(D0 + 1, pA0b, pA1b);
  write_one(D0,     pA0a, pA1a); write_one(D0 + 1, pA0b, pA1b);
  __syncthreads();  // also fences wpkl pack

// per-plane conv2 dot2 scatter body (shares wch/wrow of enclosing ch loop)
#define CONV2_PLANE(PL, AP, AC, AM)                                          \
  {                                                                          \
    half2v H0[4], HPv[4];                                                    \
    float c0[4], c1[4];                                                      \
    _Pragma("unroll")                                                        \
    for (int r = 0; r < 4; ++r) {                                            \
      const __fp16* hp = &hbuf[PL][ch][py0 + r][px0];                        \
      half2v h0 = *(const half2v*)hp;                                        \
      half2v h1 = *(const half2v*)(hp + 2);                                  \
      unsigned u0, u1;                                                       \
      __builtin_memcpy(&u0, &h0, 4);                                         \
      __builtin_memcpy(&u1, &h1, 4);                                         \
      unsigned pm = (u1 << 16) | (u0 >> 16);                                 \
      half2v hpv;                                                            \
      __builtin_memcpy(&hpv, &pm, 4);                                        \
      H0[r] = h0; HPv[r] = hpv;                                              \
      c0[r] = (float)h1.x; c1[r] = (float)h1.y;                              \
    }                                                                        \
    _Pragma("unroll")                                                        \
    for (int ky = 0; ky < 3; ++ky)                                           \
      _Pragma("unroll")                                                      \
      for (int i = 0; i < 2; ++i) {                                          \
        const int r = i + ky;                                                \
        const half2v hE = H0[r], hO = HPv[r];                                \
        const float s0v = c0[r], s1v = c1[r];                                \
        {                                                                    \
          half2v wv = wrow[ky]; float ws = wch[ky * 3 + 2];                  \
          AP[i][0] = FDOT2(hE, wv, AP[i][0]);                                \
          AP[i][0] = fmaf(ws, s0v, AP[i][0]);                                \
          AP[i][1] = FDOT2(hO, wv, AP[i][1]);                                \
          AP[i][1] = fmaf(ws, s1v, AP[i][1]);                                \
        }                                                                    \
        {                                                                    \
          half2v wv = wrow[3 + ky]; float ws = wch[9 + ky * 3 + 2];          \
          AC[i][0] = FDOT2(hE, wv, AC[i][0]);                                \
          AC[i][0] = fmaf(ws, s0v, AC[i][0]);                                \
          AC[i][1] = FDOT2(hO, wv, AC[i][1]);                                \
          AC[i][1] = fmaf(ws, s1v, AC[i][1]);                                \
        }                                                                    \
        {                                                                    \
          half2v wv = wrow[6 + ky]; float ws = wch[18 + ky * 3 + 2];         \
          AM[i][0] = FDOT2(hE, wv, AM[i][0]);                                \
          AM[i][0] = fmaf(ws, s0v, AM[i][0]);                                \
          AM[i][1] = FDOT2(hO, wv, AM[i][1]);                                \
          AM[i][1] = fmaf(ws, s1v, AM[i][1]);                                \
        }                                                                    \
      }                                                                      \
  }

  for (int k = 0; k < 17; ++k) {
    const int e = D0 - 1 + 2 * k;          // hidden pair (e, e+1)
    const bool liveA = (e >= 0);           // e <= 63 always
    const bool liveB = (e + 1 < DD);
    // prefetch next two deriv planes (global -> regs); overlaps conv1
    issue_one(e + 3, pA0a, pA1a);
    issue_one(e + 4, pA0b, pA1b);
    // prefetch prev-state operand for this phase's 2-plane store
    const bool doStore = (k >= 1);         // outputs d0=e-1, d1=e
    float2 prA0, prA1, prB0, prB1;
    prA0.x = prA0.y = prA1.x = prA1.y = 0.f;
    prB0.x = prB0.y = prB1.x = prB1.y = 0.f;
    if (doStore && !zeroPrev) {
      size_t v0 = (size_t)(e - 1) * HW + (size_t)(ty0 + py0) * WW + tx0 + px0;
      prA0 = *(const float2*)&prevBuf[v0];
      prA1 = *(const float2*)&prevBuf[v0 + WW];
      prB0 = *(const float2*)&prevBuf[v0 + HW];
      prB1 = *(const float2*)&prevBuf[v0 + HW + WW];
    }
    comp_hidden_pair(e);
    __syncthreads();  // hbuf RAW ready; all conv1 dbuf reads done
    // conv2 scatter: h(e) -> (A2,A1,A0), h(e+1) -> (A3,A2,A1)
#pragma unroll 1
    for (int ch = 0; ch < 8; ++ch) {
      const float* wch = w2 + ch * 27;
      const half2v* wrow = &wpkl[ch * 9];
      if (liveA) CONV2_PLANE(0, A2_, A1_, A0_);
      if (liveB) CONV2_PLANE(1, A3_, A2_, A1_);
    }
    // deriv planes e+3,e+4 -> LDS ring slots (e-1)&3, e&3 (freed by sync)
    write_one(e + 3, pA0a, pA1a);
    write_one(e + 4, pA0b, pA1b);
    if (doStore) {
      size_t v0 = (size_t)(e - 1) * HW + (size_t)(ty0 + py0) * WW + tx0 + px0;
      float2 o;
      o.x = prA0.x + coef * (prA0.x - A0_[0][0]);
      o.y = prA0.y + coef * (prA0.y - A0_[0][1]);
      *(float2*)&outBuf[v0] = o;
      o.x = prA1.x + coef * (prA1.x - A0_[1][0]);
      o.y = prA1.y + coef * (prA1.y - A0_[1][1]);
      *(float2*)&outBuf[v0 + WW] = o;
      o.x = prB0.x + coef * (prB0.x - A1_[0][0]);
      o.y = prB0.y + coef * (prB0.y - A1_[0][1]);
      *(float2*)&outBuf[v0 + HW] = o;
      o.x = prB1.x + coef * (prB1.x - A1_[1][0]);
      o.y = prB1.y + coef * (prB1.y - A1_[1][1]);
      *(float2*)&outBuf[v0 + HW + WW] = o;
    }
    // rotate ring by 2 (name rotation: no dynamic register indexing)
#pragma unroll
    for (int i = 0; i < 2; ++i)
#pragma unroll
      for (int j = 0; j < 2; ++j) {
        A0_[i][j] = A2_[i][j]; A1_[i][j] = A3_[i][j];
        A2_[i][j] = b2;        A3_[i][j] = b2;
      }
    __syncthreads();  // fences dbuf RAW + hbuf WAR for next phase
  }
#undef CONV2_PLANE
}

// ---------------------------------------------------------------------------
// Kernel C: t_next = fdiff_t(p,x) + fdiff_t(q,y) + fdiff_t(s,z) + zb
// ---------------------------------------------------------------------------
__global__ __launch_bounds__(256) void k_combine(
    const float* __restrict__ p, const float* __restrict__ q,
    const float* __restrict__ s_, const float* __restrict__ zb,
    float* __restrict__ tn) {
  int idx = blockIdx.x * 256 + threadIdx.x;
  int x = idx & (WW - 1);
  int y = (idx >> 8) & (HH - 1);
  int d = idx >> 16;
  float v = zb[idx];
  v += (x > 0 ? p[idx - 1] : 0.f) - (x < WW - 1 ? p[idx] : 0.f);
  v += (y > 0 ? q[idx - WW] : 0.f) - (y < HH - 1 ? q[idx] : 0.f);
  v += (d > 0 ? s_[idx - HW] : 0.f) - (d < DD - 1 ? s_[idx] : 0.f);
  tn[idx] = v;
}

// ---------------------------------------------------------------------------
extern "C" void kernel_launch(void* const* d_in, const int* in_sizes, int n_in,
                              void* d_out, int out_size, void* d_ws, size_t ws_size,
                              hipStream_t stream) {
  const float* image = (const float*)d_in[0];
  const float* sino  = (const float*)d_in[1];
  const float* W1    = (const float*)d_in[2];
  const float* B1    = (const float*)d_in[3];
  const float* W2    = (const float*)d_in[4];
  const float* B2    = (const float*)d_in[5];
  const float* ntx   = (const float*)d_in[6];
  const float* nty   = (const float*)d_in[7];
  const float* ntz   = (const float*)d_in[8];
  const float* nt    = (const float*)d_in[9];
  float* out = (float*)d_out;

  // workspace layout: corr(HW) | p | q | s | zb  -> 67.4 MB total
  float* corr = (float*)d_ws;
  float* p  = corr + HW;
  float* q  = p + NVOX;
  float* s_ = q + NVOX;
  float* zb = s_ + NVOX;

  // outs[0] = image
  hipMemcpyAsync(out, image, (size_t)NVOX * sizeof(float),
                 hipMemcpyDeviceToDevice, stream);

  for (int c = 0; c < 3; ++c) {
    const float* t = out + (size_t)c * NVOX;
    float* tn = out + (size_t)(c + 1) * NVOX;
    k_corr<<<HW / 256, 256, 0, stream>>>(t, sino, corr);
    // z: 4 basic-blocks x 2 depth chunks -> 512 blocks = 2 WG/CU
    k_blocks<<<dim3(WW / TS, HH / TS, 8), 256, 0, stream>>>(
        t, corr, p, q, s_, zb, W1, B1, W2, B2, ntx, nty, ntz, nt, c);
    k_combine<<<NVOX / 256, 256, 0, stream>>>(p, q, s_, zb, tn);
  }
}